// Round 6
// baseline (131.333 us; speedup 1.0000x reference)
//
#include <hip/hip_runtime.h>
#include <math.h>

// DecisionTrees2: out[n, idx] = prod_f softmax((x[n,f]*W + b[f]) / 0.1)[d_f]
// 512 MiB f32 output => HBM-write bound.
// R6: grid-stride "moving front" write order (like the 6.8 TB/s fill kernel).
//   float4 index g = it*524288 + bid*256 + t  =>
//     row n      = 32*it + (bid>>6)        (varies per iteration)
//     in-row j   = (bid&63)*256 + t        (FIXED per thread)
//   Each block stages bins for its 64 rows (n ≡ bid>>6 mod 32) in 8 KB LDS,
//   then streams 64 stores whose addresses advance chip-wide in lockstep.
//   hi digits (from j) are wave-uniform; lo digits are per-thread constants.

typedef float f32x4 __attribute__((ext_vector_type(4)));

__global__ __launch_bounds__(256) void dt2_kernel(const float* __restrict__ x,
                                                  const float* __restrict__ cps,
                                                  float* __restrict__ out) {
    __shared__ float bins2[64][8][4];   // [local_row][feature][bin] = 8 KB

    const int t     = threadIdx.x;
    const int bid   = blockIdx.x;
    const int rbase = bid >> 6;         // this block's rows: n = rbase + 32*l
    const int hb    = bid & 63;

    // --- stage softmaxes for 64 rows x 8 features (512 tasks, 2/thread) ---
    #pragma unroll
    for (int task = t; task < 512; task += 256) {
        const int l = task >> 3;
        const int f = task & 7;
        const int n = rbase + 32 * l;
        const float a = cps[f * 3 + 0];
        const float b = cps[f * 3 + 1];
        const float c = cps[f * 3 + 2];
        // sort 3 values
        const float lo = fminf(a, b), hi = fmaxf(a, b);
        const float c0 = fminf(lo, c);
        const float c2 = fmaxf(hi, c);
        const float c1 = fmaxf(lo, fminf(hi, c));
        // bias = cumsum of [0, -c0, -c1, -c2]
        const float b1 = -c0;
        const float b2 = b1 - c1;
        const float b3 = b2 - c2;
        const float xv = x[n * 8 + f];
        const float h0 = xv * 1.0f;
        const float h1 = xv * 2.0f + b1;
        const float h2 = xv * 3.0f + b2;
        const float h3 = xv * 4.0f + b3;
        const float m = fmaxf(fmaxf(h0, h1), fmaxf(h2, h3));
        const float e0 = __expf((h0 - m) * 10.0f);
        const float e1 = __expf((h1 - m) * 10.0f);
        const float e2 = __expf((h2 - m) * 10.0f);
        const float e3 = __expf((h3 - m) * 10.0f);
        const float inv = 1.0f / (e0 + e1 + e2 + e3);
        bins2[l][f][0] = e0 * inv;
        bins2[l][f][1] = e1 * inv;
        bins2[l][f][2] = e2 * inv;
        bins2[l][f][3] = e3 * inv;
    }
    __syncthreads();

    // hi = (hb<<2) | wid  (wave-uniform); its base-4 digits:
    const int wid = t >> 6;
    const int d0 = (hb >> 4) & 3;
    const int d1 = (hb >> 2) & 3;
    const int d2 = hb & 3;             // d3 = wid
    // lo digits (per-thread constants); d7 = vector component
    const int i4 = (t >> 4) & 3;
    const int i5 = (t >> 2) & 3;
    const int i6 = t & 3;

    f32x4* out4 = (f32x4*)out;
    const size_t gbase = (size_t)bid * 256 + t;

    #pragma unroll 4
    for (int l = 0; l < 64; ++l) {
        const float ph  = bins2[l][0][d0] * bins2[l][1][d1] *
                          bins2[l][2][d2] * bins2[l][3][wid];     // wave-uniform
        const float pl3 = bins2[l][4][i4] * bins2[l][5][i5] * bins2[l][6][i6];
        const f32x4 b7  = *(const f32x4*)&bins2[l][7][0];         // broadcast b128
        const float s   = ph * pl3;
        f32x4 v;
        v.x = s * b7.x;
        v.y = s * b7.y;
        v.z = s * b7.z;
        v.w = s * b7.w;
        __builtin_nontemporal_store(v, &out4[gbase + (size_t)l * 524288]);
    }
}

extern "C" void kernel_launch(void* const* d_in, const int* in_sizes, int n_in,
                              void* d_out, int out_size, void* d_ws, size_t ws_size,
                              hipStream_t stream) {
    const float* x   = (const float*)d_in[0];
    const float* cps = (const float*)d_in[1];
    float* out = (float*)d_out;
    dt2_kernel<<<2048, 256, 0, stream>>>(x, cps, out);
}

// Round 7
// 97.269 us; speedup vs baseline: 1.3502x; 1.3502x over previous
//
#include <hip/hip_runtime.h>
#include <math.h>

// DecisionTrees2: out[n, idx] = prod_f softmax((x[n,f]*W + b[f]) / 0.1)[d_f]
// idx digits (base 4): d0..d7; hi = d0..d3 (slow), lo = d4..d7 (fast).
// 512 MiB f32 output => HBM-write bound.
// R7: zero-dependency store loop. One row per block (best shape, R1).
//   Full unroll: wave w, iter it writes hi = 4*it + w whose digits are
//   (it>>4, (it>>2)&3, it&3, w) — compile-time. Preload bins[0..2] into 12
//   regs, fold bins[3][w] into per-thread pl constants. Store loop is
//   64 x {muls on regs + global_store_dwordx4 nt}: no LDS, no waits,
//   unbounded outstanding stores — structurally identical to fillBuffer.

typedef float f32x4 __attribute__((ext_vector_type(4)));

__global__ __launch_bounds__(256) void dt2_kernel(const float* __restrict__ x,
                                                  const float* __restrict__ cps,
                                                  float* __restrict__ out) {
    __shared__ float bins[8][4];

    const int n = blockIdx.x;
    const int t = threadIdx.x;

    // --- per-row bin softmaxes (threads 0..7, one feature each) ---
    if (t < 8) {
        const int f = t;
        const float a = cps[f * 3 + 0];
        const float b = cps[f * 3 + 1];
        const float c = cps[f * 3 + 2];
        // sort 3 values
        const float lo = fminf(a, b), hi = fmaxf(a, b);
        const float c0 = fminf(lo, c);
        const float c2 = fmaxf(hi, c);
        const float c1 = fmaxf(lo, fminf(hi, c));
        // bias = cumsum of [0, -c0, -c1, -c2]
        const float b1 = -c0;
        const float b2 = b1 - c1;
        const float b3 = b2 - c2;
        const float xv = x[n * 8 + f];
        const float h0 = xv * 1.0f;
        const float h1 = xv * 2.0f + b1;
        const float h2 = xv * 3.0f + b2;
        const float h3 = xv * 4.0f + b3;
        const float m = fmaxf(fmaxf(h0, h1), fmaxf(h2, h3));
        const float e0 = __expf((h0 - m) * 10.0f);
        const float e1 = __expf((h1 - m) * 10.0f);
        const float e2 = __expf((h2 - m) * 10.0f);
        const float e3 = __expf((h3 - m) * 10.0f);
        const float inv = 1.0f / (e0 + e1 + e2 + e3);
        bins[f][0] = e0 * inv;
        bins[f][1] = e1 * inv;
        bins[f][2] = e2 * inv;
        bins[f][3] = e3 * inv;
    }
    __syncthreads();

    // --- preload everything into registers (one-time LDS broadcasts) ---
    const int w = t >> 6;
    float B0[4], B1[4], B2[4];
    #pragma unroll
    for (int i = 0; i < 4; ++i) {
        B0[i] = bins[0][i];
        B1[i] = bins[1][i];
        B2[i] = bins[2][i];
    }
    const float plb = bins[3][w] * bins[4][(t >> 4) & 3] *
                      bins[5][(t >> 2) & 3] * bins[6][t & 3];
    const float pl0 = plb * bins[7][0];
    const float pl1 = plb * bins[7][1];
    const float pl2 = plb * bins[7][2];
    const float pl3 = plb * bins[7][3];

    // --- 64 dependency-free nontemporal stores ---
    f32x4* out4 = (f32x4*)(out + (size_t)n * 65536);
    #pragma unroll
    for (int it = 0; it < 64; ++it) {
        const float ph = B0[it >> 4] * B1[(it >> 2) & 3] * B2[it & 3];
        f32x4 v;
        v.x = ph * pl0;
        v.y = ph * pl1;
        v.z = ph * pl2;
        v.w = ph * pl3;
        __builtin_nontemporal_store(v, &out4[t + it * 256]);
    }
}

extern "C" void kernel_launch(void* const* d_in, const int* in_sizes, int n_in,
                              void* d_out, int out_size, void* d_ws, size_t ws_size,
                              hipStream_t stream) {
    const float* x   = (const float*)d_in[0];
    const float* cps = (const float*)d_in[1];
    float* out = (float*)d_out;
    const int N = in_sizes[0] / 8;  // 2048
    dt2_kernel<<<N, 256, 0, stream>>>(x, cps, out);
}